// Round 2
// baseline (451.732 us; speedup 1.0000x reference)
//
#include <hip/hip_runtime.h>
#include <hip/hip_bf16.h>
#include <stdint.h>

// MoE: E=8 experts, M=4096 tokens, K=2048 hidden, I=1408 intermediate, TOPK=2
#define EXPERTS 8
#define MTOK 4096
#define KDIM 2048
#define IDIM 1408
#define NDIM 2816   // 2*I
#define CAP  8192   // per-expert bucket capacity (worst case)

typedef __attribute__((ext_vector_type(8))) short bf16x8;
typedef __attribute__((ext_vector_type(4))) float f32x4;

__device__ __forceinline__ unsigned short f2bf(float x) {
    unsigned u = __float_as_uint(x);
    u = u + 0x7fffu + ((u >> 16) & 1u);   // RNE
    return (unsigned short)(u >> 16);
}

__device__ __forceinline__ void gload16(const void* g, void* l) {
    __builtin_amdgcn_global_load_lds(
        (const __attribute__((address_space(1))) void*)g,
        (__attribute__((address_space(3))) void*)l, 16, 0, 0);
}

// ---------------- fp32 -> bf16 conversion (vectorized) ----------------
__global__ void __launch_bounds__(256) conv_bf16(const float* __restrict__ src,
                                                 unsigned short* __restrict__ dst, int n4) {
    int i = blockIdx.x * 256 + threadIdx.x;
    int st = gridDim.x * 256;
    for (; i < n4; i += st) {
        float4 v = reinterpret_cast<const float4*>(src)[i];
        ushort4 r;
        r.x = f2bf(v.x); r.y = f2bf(v.y); r.z = f2bf(v.z); r.w = f2bf(v.w);
        reinterpret_cast<ushort4*>(dst)[i] = r;
    }
}

// ---------------- router ----------------
__global__ void __launch_bounds__(256) router(const float* __restrict__ tw,
                                              const int* __restrict__ ids,
                                              int* __restrict__ tok, float* __restrict__ wgt,
                                              int* __restrict__ cnt) {
    int m = blockIdx.x * 256 + threadIdx.x;
    if (m >= MTOK) return;
#pragma unroll
    for (int t = 0; t < 2; t++) {
        int e = ids[m * 2 + t];
        int slot = atomicAdd(&cnt[e], 1);
        tok[e * CAP + slot] = m;
        wgt[e * CAP + slot] = tw[m * 2 + t];
    }
}

__global__ void scan_off(const int* __restrict__ cnt, int* __restrict__ off) {
    if (threadIdx.x == 0) {
        int s = 0;
        for (int e = 0; e < EXPERTS; e++) { off[e] = s; s += cnt[e]; }
    }
}

// ====================================================================
// 256x256 tile, BK=32, 8 waves (2Mx4N), 4-deep LDS pipeline, counted vmcnt.
// LDS buf (32KB): A[256 rows][64B] at +0, B[256 rows][64B] at +16384.
// Swizzle: 16B slot g = lg ^ ((row>>1)&3), both on staged source and ds_read.
// ====================================================================

// ---------------- GEMM1 + SiLU*up -> act (bf16) ----------------
__global__ void __launch_bounds__(512, 2) gemm1_silu(
    const unsigned short* __restrict__ hsb,
    const unsigned short* __restrict__ w1b,
    const int* __restrict__ tok,
    const int* __restrict__ cnt,
    const int* __restrict__ off,
    unsigned short* __restrict__ act) {
    const int cb = blockIdx.x;   // 0..10 (11 * 128 = 1408 I-cols)
    const int rb = blockIdx.y;   // 0..31
    const int e  = blockIdx.z;
    const int cnt_e = cnt[e];
    if (rb * 256 >= cnt_e) return;
    const int off_e = off[e];
    const int NT = KDIM / 32;    // 64

    __shared__ __align__(16) char smem[131072];
    __shared__ int toks[256];

    const int tid = threadIdx.x;
    const int lane = tid & 63;
    const int w = tid >> 6;
    if (tid < 256) {
        int slot = rb * 256 + tid;
        toks[tid] = (slot < cnt_e) ? tok[e * CAP + slot] : 0;
    }
    __syncthreads();

    // staging geometry: 2 A-chunks + 2 B-chunks of 16B per thread, linear LDS dest
    const int offA0 = tid * 16;             // rows 0..127
    const int offA1 = 8192 + tid * 16;      // rows 128..255
    const int rowA0 = offA0 >> 6, rowA1 = offA1 >> 6;
    const int gA0 = (tid & 3) ^ ((rowA0 >> 1) & 3);
    const int gA1 = (tid & 3) ^ ((rowA1 >> 1) & 3);
    const size_t srcA0 = (size_t)toks[rowA0] * KDIM + gA0 * 8;
    const size_t srcA1 = (size_t)toks[rowA1] * KDIM + gA1 * 8;

    const size_t w1base = (size_t)e * NDIM * KDIM;
    const int G0 = rowA0 >> 4, G1 = rowA1 >> 4;
    const int w1row0 = ((G0 & 1) ? IDIM : 0) + cb * 128 + (G0 >> 1) * 16 + (rowA0 & 15);
    const int w1row1 = ((G1 & 1) ? IDIM : 0) + cb * 128 + (G1 >> 1) * 16 + (rowA1 & 15);
    const size_t srcB0 = w1base + (size_t)w1row0 * KDIM + gA0 * 8;
    const size_t srcB1 = w1base + (size_t)w1row1 * KDIM + gA1 * 8;

    const int wr = w >> 2, wc = w & 3;          // 2 x 4 wave grid
    const int l16 = lane & 15, lg = lane >> 4;

    f32x4 acc[8][4];
#pragma unroll
    for (int m = 0; m < 8; m++)
#pragma unroll
        for (int n = 0; n < 4; n++) acc[m][n] = {0.f, 0.f, 0.f, 0.f};

#define STAGE1(s) { \
    char* sb_ = smem + (((s) & 3) << 15); \
    const int kof_ = (s) * 32; \
    gload16(hsb + srcA0 + kof_, sb_ + tid * 16); \
    gload16(hsb + srcA1 + kof_, sb_ + 8192 + tid * 16); \
    gload16(w1b + srcB0 + kof_, sb_ + 16384 + tid * 16); \
    gload16(w1b + srcB1 + kof_, sb_ + 24576 + tid * 16); }

    STAGE1(0); STAGE1(1); STAGE1(2);
    asm volatile("s_waitcnt vmcnt(8)");
    __builtin_amdgcn_sched_barrier(0);
    asm volatile("s_barrier" ::: "memory");
    __builtin_amdgcn_sched_barrier(0);

    for (int t = 0; t < NT; ++t) {
        char* db = smem + ((t & 3) << 15);
        if (t + 3 < NT) STAGE1(t + 3);

        bf16x8 b[4];
#pragma unroll
        for (int n = 0; n < 4; n++) {
            int r = wc * 64 + n * 16 + l16;
            b[n] = *reinterpret_cast<bf16x8*>(db + 16384 + r * 64 + ((lg ^ ((r >> 1) & 3)) * 16));
        }
#pragma unroll
        for (int q = 0; q < 4; q++) {
            int r0 = wr * 128 + (2 * q) * 16 + l16;
            int r1 = r0 + 16;
            bf16x8 a0 = *reinterpret_cast<bf16x8*>(db + r0 * 64 + ((lg ^ ((r0 >> 1) & 3)) * 16));
            bf16x8 a1 = *reinterpret_cast<bf16x8*>(db + r1 * 64 + ((lg ^ ((r1 >> 1) & 3)) * 16));
            __builtin_amdgcn_s_setprio(1);
#pragma unroll
            for (int n = 0; n < 4; n++) {
                acc[2 * q][n]     = __builtin_amdgcn_mfma_f32_16x16x32_bf16(a0, b[n], acc[2 * q][n], 0, 0, 0);
                acc[2 * q + 1][n] = __builtin_amdgcn_mfma_f32_16x16x32_bf16(a1, b[n], acc[2 * q + 1][n], 0, 0, 0);
            }
            __builtin_amdgcn_s_setprio(0);
        }
        __builtin_amdgcn_sched_barrier(0);
        if (t + 1 < NT) {
            if (t + 3 < NT)      { asm volatile("s_waitcnt vmcnt(8)"); }
            else if (t + 2 < NT) { asm volatile("s_waitcnt vmcnt(4)"); }
            else                 { asm volatile("s_waitcnt vmcnt(0)"); }
            asm volatile("s_barrier" ::: "memory");
            __builtin_amdgcn_sched_barrier(0);
        }
    }
#undef STAGE1

    // epilogue: within wave, n pairs (0,1),(2,3) are (gate,up) on same 16 cols
#pragma unroll
    for (int m = 0; m < 8; m++) {
#pragma unroll
        for (int p = 0; p < 2; p++) {
            f32x4 g4 = acc[m][p * 2];
            f32x4 u4 = acc[m][p * 2 + 1];
            int icol = cb * 128 + (wc * 2 + p) * 16 + l16;
#pragma unroll
            for (int j = 0; j < 4; j++) {
                int grow = rb * 256 + wr * 128 + m * 16 + lg * 4 + j;
                if (grow < cnt_e) {
                    float gt = g4[j], up = u4[j];
                    float s = gt / (1.f + __expf(-gt));
                    act[(size_t)(off_e + grow) * IDIM + icol] = f2bf(s * up);
                }
            }
        }
    }
}

// ---------------- GEMM2 + weighted scatter ----------------
__global__ void __launch_bounds__(512, 2) gemm2_scatter(
    const unsigned short* __restrict__ act,
    const unsigned short* __restrict__ w2b,
    const int* __restrict__ tok,
    const float* __restrict__ wgt,
    const int* __restrict__ cnt,
    const int* __restrict__ off,
    float* __restrict__ out) {
    const int cb = blockIdx.x;   // 0..7 (8*256 = 2048 out cols)
    const int rb = blockIdx.y;
    const int e  = blockIdx.z;
    const int cnt_e = cnt[e];
    if (rb * 256 >= cnt_e) return;
    const int off_e = off[e];
    const int NT = IDIM / 32;    // 44

    __shared__ __align__(16) char smem[131072];
    __shared__ int toks[256];
    __shared__ float wgts[256];

    const int tid = threadIdx.x;
    const int lane = tid & 63;
    const int w = tid >> 6;
    if (tid < 256) {
        int slot = rb * 256 + tid;
        bool v = slot < cnt_e;
        toks[tid] = v ? tok[e * CAP + slot] : 0;
        wgts[tid] = v ? wgt[e * CAP + slot] : 0.f;
    }
    __syncthreads();

    const int offA0 = tid * 16;
    const int offA1 = 8192 + tid * 16;
    const int rowA0 = offA0 >> 6, rowA1 = offA1 >> 6;
    const int gA0 = (tid & 3) ^ ((rowA0 >> 1) & 3);
    const int gA1 = (tid & 3) ^ ((rowA1 >> 1) & 3);
    const int s0 = rb * 256 + rowA0, s1 = rb * 256 + rowA1;
    const size_t srcA0 = (size_t)(off_e + (s0 < cnt_e ? s0 : 0)) * IDIM + gA0 * 8;
    const size_t srcA1 = (size_t)(off_e + (s1 < cnt_e ? s1 : 0)) * IDIM + gA1 * 8;

    const size_t w2base = (size_t)e * KDIM * IDIM;
    const size_t srcB0 = w2base + (size_t)(cb * 256 + rowA0) * IDIM + gA0 * 8;
    const size_t srcB1 = w2base + (size_t)(cb * 256 + rowA1) * IDIM + gA1 * 8;

    const int wr = w >> 2, wc = w & 3;
    const int l16 = lane & 15, lg = lane >> 4;

    f32x4 acc[8][4];
#pragma unroll
    for (int m = 0; m < 8; m++)
#pragma unroll
        for (int n = 0; n < 4; n++) acc[m][n] = {0.f, 0.f, 0.f, 0.f};

#define STAGE2(s) { \
    char* sb_ = smem + (((s) & 3) << 15); \
    const int kof_ = (s) * 32; \
    gload16(act + srcA0 + kof_, sb_ + tid * 16); \
    gload16(act + srcA1 + kof_, sb_ + 8192 + tid * 16); \
    gload16(w2b + srcB0 + kof_, sb_ + 16384 + tid * 16); \
    gload16(w2b + srcB1 + kof_, sb_ + 24576 + tid * 16); }

    STAGE2(0); STAGE2(1); STAGE2(2);
    asm volatile("s_waitcnt vmcnt(8)");
    __builtin_amdgcn_sched_barrier(0);
    asm volatile("s_barrier" ::: "memory");
    __builtin_amdgcn_sched_barrier(0);

    for (int t = 0; t < NT; ++t) {
        char* db = smem + ((t & 3) << 15);
        if (t + 3 < NT) STAGE2(t + 3);

        bf16x8 b[4];
#pragma unroll
        for (int n = 0; n < 4; n++) {
            int r = wc * 64 + n * 16 + l16;
            b[n] = *reinterpret_cast<bf16x8*>(db + 16384 + r * 64 + ((lg ^ ((r >> 1) & 3)) * 16));
        }
#pragma unroll
        for (int q = 0; q < 4; q++) {
            int r0 = wr * 128 + (2 * q) * 16 + l16;
            int r1 = r0 + 16;
            bf16x8 a0 = *reinterpret_cast<bf16x8*>(db + r0 * 64 + ((lg ^ ((r0 >> 1) & 3)) * 16));
            bf16x8 a1 = *reinterpret_cast<bf16x8*>(db + r1 * 64 + ((lg ^ ((r1 >> 1) & 3)) * 16));
            __builtin_amdgcn_s_setprio(1);
#pragma unroll
            for (int n = 0; n < 4; n++) {
                acc[2 * q][n]     = __builtin_amdgcn_mfma_f32_16x16x32_bf16(a0, b[n], acc[2 * q][n], 0, 0, 0);
                acc[2 * q + 1][n] = __builtin_amdgcn_mfma_f32_16x16x32_bf16(a1, b[n], acc[2 * q + 1][n], 0, 0, 0);
            }
            __builtin_amdgcn_s_setprio(0);
        }
        __builtin_amdgcn_sched_barrier(0);
        if (t + 1 < NT) {
            if (t + 3 < NT)      { asm volatile("s_waitcnt vmcnt(8)"); }
            else if (t + 2 < NT) { asm volatile("s_waitcnt vmcnt(4)"); }
            else                 { asm volatile("s_waitcnt vmcnt(0)"); }
            asm volatile("s_barrier" ::: "memory");
            __builtin_amdgcn_sched_barrier(0);
        }
    }
#undef STAGE2

    // scatter: out[token, k] += weight * y  (TOPK=2, fp32 atomic add)
#pragma unroll
    for (int m = 0; m < 8; m++) {
#pragma unroll
        for (int n = 0; n < 4; n++) {
            int kcol = cb * 256 + wc * 64 + n * 16 + l16;
#pragma unroll
            for (int j = 0; j < 4; j++) {
                int lrow = wr * 128 + m * 16 + lg * 4 + j;
                if (rb * 256 + lrow < cnt_e) {
                    atomicAdd(&out[(size_t)toks[lrow] * KDIM + kcol],
                              wgts[lrow] * acc[m][n][j]);
                }
            }
        }
    }
}

extern "C" void kernel_launch(void* const* d_in, const int* in_sizes, int n_in,
                              void* d_out, int out_size, void* d_ws, size_t ws_size,
                              hipStream_t stream) {
    const float* hs  = (const float*)d_in[0];
    const float* w1  = (const float*)d_in[1];
    const float* w2  = (const float*)d_in[2];
    const float* tw  = (const float*)d_in[3];
    const int*   ids = (const int*)d_in[4];
    float* out = (float*)d_out;

    char* ws = (char*)d_ws;
    unsigned short* w1b  = (unsigned short*)(ws);                  //  92,274,688
    unsigned short* w2b  = (unsigned short*)(ws + 92274688ull);    //  46,137,344
    unsigned short* hsb  = (unsigned short*)(ws + 138412032ull);   //  16,777,216
    unsigned short* actb = (unsigned short*)(ws + 155189248ull);   //  23,068,672
    int*   tokb = (int*)  (ws + 178257920ull);
    float* wgtb = (float*)(ws + 178520064ull);
    int*   cntb = (int*)  (ws + 178782208ull);
    int*   offb = (int*)  (ws + 178782240ull);

    hipMemsetAsync(d_out, 0, (size_t)MTOK * KDIM * sizeof(float), stream);
    hipMemsetAsync(cntb, 0, 64, stream);

    conv_bf16<<<4096, 256, 0, stream>>>(w1, w1b, EXPERTS * NDIM * KDIM / 4);
    conv_bf16<<<2048, 256, 0, stream>>>(w2, w2b, EXPERTS * KDIM * IDIM / 4);
    conv_bf16<<<1024, 256, 0, stream>>>(hs, hsb, MTOK * KDIM / 4);

    router<<<MTOK / 256, 256, 0, stream>>>(tw, ids, tokb, wgtb, cntb);
    scan_off<<<1, 64, 0, stream>>>(cntb, offb);

    gemm1_silu<<<dim3(11, 32, 8), 512, 0, stream>>>(hsb, w1b, tokb, cntb, offb, actb);
    gemm2_scatter<<<dim3(8, 32, 8), 512, 0, stream>>>(actb, w2b, tokb, wgtb, cntb, offb, out);
}